// Round 2
// baseline (817.522 us; speedup 1.0000x reference)
//
#include <hip/hip_runtime.h>

// RNN_64072322122514: B=4096, T=2048, F=8, H=32, O=8 Elman RNN, all fp32 I/O.
//   h_t = tanh(x_t @ W_ih^T + b_ih + b_hh + h_{t-1} @ W_hh^T);  y = h_T @ W_out^T + b_out
//
// R7 (resubmit — R1 bench was GPUAcquisitionTimeout, no data): LDS-FREE
// RECURRENCE. R6 counters: VALUBusy 64%, occ 20.7%, HBM 3.8%, 516 clk/step
// vs ~165 clk issue -> latency-bound on 3 serial DS round-trips per step
// (2x ds_read_b128 gather, 2x ds_swizzle combine, ds_write_b16 publish),
// ~300+ cyc of loop-carried LDS latency that 2 waves/SIMD can't hide.
// Replace all in-loop DS traffic with register cross-lane ops:
//   - k-half combine (lane^16): v_permlane16_swap_b32, used orientation-
//     robustly (only P+Q consumed, = s_own + s_partner either way).
//   - each lane computes BOTH tanh of its dim-pair (has both full sums),
//     keeps h-pair packed fp16 in VGPR pk.
//   - next-step gather of 8 h-pairs from pk: row_ror:8 + cndmask fix
//     (aligns pair-bit3 to k-half bit4), then 7-mov DPP xor-tree
//     (quad_perm xor1/xor2, row_half_mirror) => pairs q^0..q^7.
//   - weights re-indexed per lane: wA[j] covers h-pair (q^j), q=(ll&7)|(c<<3).
// Same math order + RTE fp16 -> bit-identical state evolution vs R6.
// Predict: 441 -> ~250-310 us, VALUBusy -> ~90%, absmax unchanged.

typedef float v2f __attribute__((ext_vector_type(2)));
typedef _Float16 h2v __attribute__((ext_vector_type(2)));

static constexpr int T_STEPS = 2048;
static constexpr int FDIM    = 8;
static constexpr int HDIM    = 32;
static constexpr int ODIM    = 8;
static constexpr int ROWS_PER_BLOCK = 8;    // 4 waves x 2 rows
static constexpr int GROUP   = 4;           // steps per prefetch group
static constexpr int NGROUP  = T_STEPS / GROUP;   // 512 (even)

__device__ __forceinline__ float fdot2(h2v a, h2v b, float c) {
    return __builtin_amdgcn_fdot2(a, b, c, false);
}
__device__ __forceinline__ h2v bch(unsigned u) {
    return __builtin_bit_cast(h2v, u);
}

// dst[lane] = src[dpp_sel(lane)], all lanes active, no bound effects.
template <int CTRL>
__device__ __forceinline__ unsigned dppmov(unsigned v) {
    return (unsigned)__builtin_amdgcn_mov_dpp((int)v, CTRL, 0xF, 0xF, true);
}
static constexpr int DPP_XOR1 = 0xB1;   // quad_perm [1,0,3,2]
static constexpr int DPP_XOR2 = 0x4E;   // quad_perm [2,3,0,1]
static constexpr int DPP_HMIR = 0x141;  // row_half_mirror (xor 7 within 8)
static constexpr int DPP_ROR8 = 0x128;  // row_ror:8 (xor 8 within 16)

// Returns s + s_partner where partner = lane^16. Orientation-robust use of
// v_permlane16_swap_b32: whichever of {a,b} ends up holding the even/odd
// 16-row values, a+b is own+partner. s_nop covers the VALU->permlane
// read-after-write wait-state requirement inside the asm block.
__device__ __forceinline__ float xor16_sum(float s) {
    float a = s, b;
    asm("v_mov_b32 %1, %0\n\t"
        "s_nop 1\n\t"
        "v_permlane16_swap_b32 %0, %1"
        : "+v"(a), "=&v"(b));
    return a + b;
}

__global__ __launch_bounds__(256, 2) void rnn_scan_kernel(
    const float* __restrict__ x,      // [B, T, F]
    const float* __restrict__ W_ih,   // [H, F]
    const float* __restrict__ W_hh,   // [H, H]
    const float* __restrict__ b_ih,   // [H]
    const float* __restrict__ b_hh,   // [H]
    const float* __restrict__ W_out,  // [O, H]
    const float* __restrict__ b_out,  // [O]
    float* __restrict__ out)          // [1, B, O]
{
    const float K = 2.8853900817779268f;  // 2*log2(e)
    const int tid  = threadIdx.x;
    const int lane = tid & 63;
    const int wave = tid >> 6;
    const int ll   = lane & 31;           // lane within row
    const int pr   = ll & 15;             // dim-pair: dims {2pr, 2pr+1}
    const int c    = ll >> 4;             // k-half c: pairs [8c,8c+8), f-half [4c,4c+4)
    const int sub  = lane >> 5;           // which of the wave's 2 rows
    const int r    = wave * 2 + sub;      // row within block
    const long long b = (long long)blockIdx.x * ROWS_PER_BLOCK + r;
    const int d0 = 2 * pr, d1 = 2 * pr + 1;
    const int q  = (ll & 7) | (c << 3);   // gather-tree base pair
    const bool fixflag = (((ll >> 3) & 1) != c);  // needs ror8 realign

    __shared__ _Float16 hsh[ROWS_PER_BLOCK][HDIM];   // epilogue only

    // ---- resident weights (fp16, pre-scaled by K), tree-gather order ----
    h2v wA[8], wB[8];     // wA[j]/wB[j] cover h-pair (q^j)
    const float* whr0 = W_hh + d0 * HDIM;
    const float* whr1 = W_hh + d1 * HDIM;
#pragma unroll
    for (int j = 0; j < 8; ++j) {
        const int kk = 2 * (q ^ j);
        h2v wa; wa[0] = (_Float16)(whr0[kk] * K); wa[1] = (_Float16)(whr0[kk + 1] * K);
        wA[j] = wa;
        h2v wb; wb[0] = (_Float16)(whr1[kk] * K); wb[1] = (_Float16)(whr1[kk + 1] * K);
        wB[j] = wb;
    }
    v2f wiv[4];           // xp weights (fp32) for f in [4c, 4c+4)
#pragma unroll
    for (int f = 0; f < 4; ++f) {
        v2f w; w[0] = W_ih[d0 * FDIM + 4 * c + f] * K;
               w[1] = W_ih[d1 * FDIM + 4 * c + f] * K;
        wiv[f] = w;
    }
    v2f bias2;            // bias added once (by the c=0 half)
    bias2[0] = c ? 0.0f : (b_ih[d0] + b_hh[d0]) * K;
    bias2[1] = c ? 0.0f : (b_ih[d1] + b_hh[d1]) * K;

    const float4* xq = reinterpret_cast<const float4*>(x + (size_t)b * T_STEPS * FDIM);

    unsigned pk = 0u;     // packed fp16 h-pair (h[2pr], h[2pr+1]); h_0 = 0

#define LOADG(buf, gi)                                                         \
    {                                                                          \
        const int base = (gi) * (2 * GROUP) + c;                               \
        _Pragma("unroll")                                                      \
        for (int k = 0; k < GROUP; ++k) buf[k] = xq[base + 2 * k];             \
    }                                                                          \
    asm volatile("" ::: "memory");

#define STEP(xr)                                                               \
    {                                                                          \
        /* rebuild this lane's 8 h-pairs from pk (pure DPP, no LDS) */         \
        unsigned t8 = dppmov<DPP_ROR8>(pk);                                    \
        unsigned g0 = fixflag ? t8 : pk;   /* pair q   */                      \
        unsigned g1 = dppmov<DPP_XOR1>(g0);    /* q^1 */                       \
        unsigned g2 = dppmov<DPP_XOR2>(g0);    /* q^2 */                       \
        unsigned g3 = dppmov<DPP_XOR1>(g2);    /* q^3 */                       \
        unsigned g4 = dppmov<DPP_HMIR>(g3);    /* q^4 */                       \
        unsigned g5 = dppmov<DPP_HMIR>(g2);    /* q^5 */                       \
        unsigned g6 = dppmov<DPP_HMIR>(g1);    /* q^6 */                       \
        unsigned g7 = dppmov<DPP_HMIR>(g0);    /* q^7 */                       \
        float c00 = 0.0f, c01 = 0.0f, c10 = 0.0f, c11 = 0.0f;                  \
        c00 = fdot2(wA[0], bch(g0), c00);  c10 = fdot2(wB[0], bch(g0), c10);   \
        c01 = fdot2(wA[4], bch(g4), c01);  c11 = fdot2(wB[4], bch(g4), c11);   \
        c00 = fdot2(wA[1], bch(g1), c00);  c10 = fdot2(wB[1], bch(g1), c10);   \
        c01 = fdot2(wA[5], bch(g5), c01);  c11 = fdot2(wB[5], bch(g5), c11);   \
        c00 = fdot2(wA[2], bch(g2), c00);  c10 = fdot2(wB[2], bch(g2), c10);   \
        c01 = fdot2(wA[6], bch(g6), c01);  c11 = fdot2(wB[6], bch(g6), c11);   \
        c00 = fdot2(wA[3], bch(g3), c00);  c10 = fdot2(wB[3], bch(g3), c10);   \
        c01 = fdot2(wA[7], bch(g7), c01);  c11 = fdot2(wB[7], bch(g7), c11);   \
        v2f acc = bias2;                                                       \
        v2f t;                                                                 \
        t[0] = xr.x; t[1] = xr.x;  acc = __builtin_elementwise_fma(wiv[0], t, acc); \
        t[0] = xr.y; t[1] = xr.y;  acc = __builtin_elementwise_fma(wiv[1], t, acc); \
        t[0] = xr.z; t[1] = xr.z;  acc = __builtin_elementwise_fma(wiv[2], t, acc); \
        t[0] = xr.w; t[1] = xr.w;  acc = __builtin_elementwise_fma(wiv[3], t, acc); \
        float s0 = xor16_sum(acc[0] + (c00 + c01));                            \
        float s1 = xor16_sum(acc[1] + (c10 + c11));                            \
        float e0 = __builtin_amdgcn_exp2f(s0);                                 \
        float e1 = __builtin_amdgcn_exp2f(s1);                                 \
        float r0v = __builtin_amdgcn_rcpf(e0 + 1.0f);                          \
        float r1v = __builtin_amdgcn_rcpf(e1 + 1.0f);                          \
        h2v hv;                                                                \
        hv[0] = (_Float16)fmaf(-2.0f, r0v, 1.0f);                              \
        hv[1] = (_Float16)fmaf(-2.0f, r1v, 1.0f);                              \
        pk = __builtin_bit_cast(unsigned, hv);                                 \
    }

#define STEPS(buf) STEP(buf[0]) STEP(buf[1]) STEP(buf[2]) STEP(buf[3])

    float4 bufA[GROUP], bufB[GROUP];
    LOADG(bufA, 0)

    for (int gi = 0; gi < NGROUP; gi += 2) {
        LOADG(bufB, gi + 1)
        STEPS(bufA)
        {
            const int gn = (gi + 2 < NGROUP) ? (gi + 2) : (NGROUP - 1);
            LOADG(bufA, gn)
        }
        STEPS(bufB)
    }
#undef STEPS
#undef STEP
#undef LOADG

    // ---- epilogue: publish final h once, then y = h_T @ W_out^T + b_out ----
    if (c == 0)
        *reinterpret_cast<h2v*>(&hsh[r][2 * pr]) = bch(pk);
    __syncthreads();
    if (tid < ROWS_PER_BLOCK * ODIM) {   // 64 threads
        const int rr = tid >> 3;
        const int o  = tid & 7;
        float acc = b_out[o];
#pragma unroll
        for (int j = 0; j < HDIM; ++j)
            acc = fmaf((float)hsh[rr][j], W_out[o * HDIM + j], acc);
        out[((long long)blockIdx.x * ROWS_PER_BLOCK + rr) * ODIM + o] = acc;
    }
}

extern "C" void kernel_launch(void* const* d_in, const int* in_sizes, int n_in,
                              void* d_out, int out_size, void* d_ws, size_t ws_size,
                              hipStream_t stream) {
    const float* x     = (const float*)d_in[0];
    const float* W_ih  = (const float*)d_in[1];
    const float* W_hh  = (const float*)d_in[2];
    const float* b_ih  = (const float*)d_in[3];
    const float* b_hh  = (const float*)d_in[4];
    const float* W_out = (const float*)d_in[5];
    const float* b_out = (const float*)d_in[6];

    const int B = in_sizes[0] / (T_STEPS * FDIM);   // 4096
    const int grid = B / ROWS_PER_BLOCK;            // 512 blocks = 2/CU

    rnn_scan_kernel<<<grid, 256, 0, stream>>>(
        x, W_ih, W_hh, b_ih, b_hh, W_out, b_out, (float*)d_out);
}

// Round 5
// 666.423 us; speedup vs baseline: 1.2267x; 1.2267x over previous
//
#include <hip/hip_runtime.h>

// RNN_64072322122514: B=4096, T=2048, F=8, H=32, O=8 Elman RNN, all fp32 I/O.
//   h_t = tanh(x_t @ W_ih^T + b_ih + b_hh + h_{t-1} @ W_hh^T);  y = h_T @ W_out^T + b_out
//
// R8b (R4 was a compile error: STEP's local `float s` collided with CHUNK's
// `for (int s...)` loop var — for-init scope rule. Renamed s->sv, loop->st.
// No semantic change.)
// R8 post-mortem of R7: stall (~180 clk/SIMD-step) did NOT move when all
// in-loop LDS was removed -> stall is NOT the h-LDS chain (TLP hides it).
// R7 added ~180 busy clk (DPP tree + 2x tanh + asm movs) -> 589 us. Revert
// to R6 core (330 busy). Stall attribution: x global-load latency — VGPR
// counts (44/32) prove bufA/bufB were never register-resident, so the
// "4-step prefetch" had ~no real lead. Fix: stage x through LDS:
//   - 1x global_load_lds (16 B/lane, 1 KB/wave = 16 steps x 2 rows) per
//     chunk, double-buffered in SEPARATE __shared__ arrays xA/xB (backend
//     can disambiguate -> no conservative vmcnt(0) before ds_reads).
//   - issued a full chunk ahead (~3000 clk lead >> 900 HBM), counted
//     s_waitcnt vmcnt(1) at chunk boundaries (T4: never drain to 0 in
//     steady state). Chunks are wave-private: no __syncthreads.
//   - per step x is one broadcast ds_read_b128 with imm offset.
//   - h combine: v_permlane16_swap sum (proven bit-identical in R7)
//     replaces 2x ds_swizzle; ONE tanh per lane (R6 style).
// Predict: 441 -> ~300-330 us, VALUBusy -> 82-92%, absmax 0.00390625.

typedef float v2f __attribute__((ext_vector_type(2)));
typedef _Float16 h2v __attribute__((ext_vector_type(2)));

static constexpr int T_STEPS = 2048;
static constexpr int FDIM    = 8;
static constexpr int HDIM    = 32;
static constexpr int ODIM    = 8;
static constexpr int ROWS_PER_BLOCK = 8;    // 4 waves x 2 rows
static constexpr int NWAVE   = 4;
static constexpr int CH      = 16;          // steps per chunk = 1 KB per wave
static constexpr int NCH     = T_STEPS / CH;   // 128 (even)
static constexpr int LSTR    = 40;          // fp16 LDS row stride for h

__device__ __forceinline__ float fdot2(h2v a, h2v b, float c) {
    return __builtin_amdgcn_fdot2(a, b, c, false);
}
__device__ __forceinline__ h2v bch(unsigned u) {
    return __builtin_bit_cast(h2v, u);
}

// Returns s + s_partner where partner = lane^16 (orientation-robust use of
// v_permlane16_swap_b32; proven bit-identical vs ds_swizzle xor16 in R7).
__device__ __forceinline__ float xor16_sum(float s) {
    float a = s, b;
    asm("v_mov_b32 %1, %0\n\t"
        "s_nop 1\n\t"
        "v_permlane16_swap_b32 %0, %1"
        : "+v"(a), "=&v"(b));
    return a + b;
}

// async global->LDS, 16 B per lane; lds dest = uniform base + lane*16.
__device__ __forceinline__ void gload_lds16(const void* g, void* l) {
    __builtin_amdgcn_global_load_lds(
        (const __attribute__((address_space(1))) void*)g,
        (__attribute__((address_space(3))) void*)l, 16, 0, 0);
}

__global__ __launch_bounds__(256, 2) void rnn_scan_kernel(
    const float* __restrict__ x,      // [B, T, F]
    const float* __restrict__ W_ih,   // [H, F]
    const float* __restrict__ W_hh,   // [H, H]
    const float* __restrict__ b_ih,   // [H]
    const float* __restrict__ b_hh,   // [H]
    const float* __restrict__ W_out,  // [O, H]
    const float* __restrict__ b_out,  // [O]
    float* __restrict__ out)          // [1, B, O]
{
    const float K = 2.8853900817779268f;  // 2*log2(e)
    const int tid  = threadIdx.x;
    const int lane = tid & 63;
    const int wave = tid >> 6;
    const int g    = lane & 15;           // dim-pair: dims {2g, 2g+1}
    const int c    = (lane >> 4) & 1;     // k-half [16c,16c+16), f-half [4c,4c+4)
    const int sub  = lane >> 5;           // which of the wave's 2 rows
    const int r    = wave * 2 + sub;      // row within block
    const int d0 = 2 * g, d1 = 2 * g + 1;

    __shared__ _Float16 hsh[ROWS_PER_BLOCK][LSTR];
    __shared__ alignas(16) float xA[NWAVE][CH * 16];   // [wave][16 steps x 2 rows x 32B]
    __shared__ alignas(16) float xB[NWAVE][CH * 16];

    // ---- resident weights (fp16, pre-scaled by K) ----
    h2v wA[8], wB[8];     // dims d0/d1 over k in [16c, 16c+16)
    const float* whr0 = W_hh + d0 * HDIM + 16 * c;
    const float* whr1 = W_hh + d1 * HDIM + 16 * c;
#pragma unroll
    for (int j = 0; j < 8; ++j) {
        h2v wa; wa[0] = (_Float16)(whr0[2 * j] * K); wa[1] = (_Float16)(whr0[2 * j + 1] * K);
        wA[j] = wa;
        h2v wb; wb[0] = (_Float16)(whr1[2 * j] * K); wb[1] = (_Float16)(whr1[2 * j + 1] * K);
        wB[j] = wb;
    }
    v2f wiv[4];           // xp weights (fp32) for f in [4c, 4c+4)
#pragma unroll
    for (int f = 0; f < 4; ++f) {
        v2f w; w[0] = W_ih[d0 * FDIM + 4 * c + f] * K;
               w[1] = W_ih[d1 * FDIM + 4 * c + f] * K;
        wiv[f] = w;
    }
    v2f bias2;            // bias added once (by the c=0 half)
    bias2[0] = c ? 0.0f : (b_ih[d0] + b_hh[d0]) * K;
    bias2[1] = c ? 0.0f : (b_ih[d1] + b_hh[d1]) * K;

    hsh[r][2 * g + c] = (_Float16)0.0f;   // h_0 = 0 (covers all 32 dims)

    // h gather/publish pointers (R6 scheme)
    const uint4* hq = reinterpret_cast<const uint4*>(
        reinterpret_cast<const char*>(&hsh[r][0]) + 32 * c);
    _Float16* hw = &hsh[r][2 * g + c];

    // ---- x staging: lane i stages (row = i>>5, step = (i&31)>>1, half = i&1)
    // writer lane i lands at byte i*16 = sub*512 + step*32 + half*16  (matches reader)
    const int sj = lane & 31;
    const float* gsrc = x
        + ((size_t)blockIdx.x * ROWS_PER_BLOCK + wave * 2 + (lane >> 5)) * ((size_t)T_STEPS * FDIM)
        + (size_t)(sj >> 1) * FDIM + (size_t)(sj & 1) * 4;
    float* ldstA = &xA[wave][0];          // wave-uniform LDS base
    float* ldstB = &xB[wave][0];
    // reader base: this lane reads its row's f-half each step
    const char* rdA = reinterpret_cast<const char*>(&xA[wave][0]) + sub * 512 + c * 16;
    const char* rdB = reinterpret_cast<const char*>(&xB[wave][0]) + sub * 512 + c * 16;

#define ISSUE(dst, chunk) gload_lds16(gsrc + (size_t)(chunk) * (CH * FDIM), dst);

#define STEP(PBASE, S)                                                         \
    {                                                                          \
        float4 xr = *reinterpret_cast<const float4*>((PBASE) + (S) * 32);      \
        uint4 u0 = hq[0], u1 = hq[1];                                          \
        float c00 = 0.0f, c01 = 0.0f, c10 = 0.0f, c11 = 0.0f;                  \
        c00 = fdot2(wA[0], bch(u0.x), c00);  c10 = fdot2(wB[0], bch(u0.x), c10); \
        c01 = fdot2(wA[4], bch(u1.x), c01);  c11 = fdot2(wB[4], bch(u1.x), c11); \
        c00 = fdot2(wA[1], bch(u0.y), c00);  c10 = fdot2(wB[1], bch(u0.y), c10); \
        c01 = fdot2(wA[5], bch(u1.y), c01);  c11 = fdot2(wB[5], bch(u1.y), c11); \
        c00 = fdot2(wA[2], bch(u0.z), c00);  c10 = fdot2(wB[2], bch(u0.z), c10); \
        c01 = fdot2(wA[6], bch(u1.z), c01);  c11 = fdot2(wB[6], bch(u1.z), c11); \
        c00 = fdot2(wA[3], bch(u0.w), c00);  c10 = fdot2(wB[3], bch(u0.w), c10); \
        c01 = fdot2(wA[7], bch(u1.w), c01);  c11 = fdot2(wB[7], bch(u1.w), c11); \
        v2f a = bias2;                                                         \
        v2f t;                                                                 \
        t[0] = xr.x; t[1] = xr.x;  a = __builtin_elementwise_fma(wiv[0], t, a); \
        t[0] = xr.y; t[1] = xr.y;  a = __builtin_elementwise_fma(wiv[1], t, a); \
        t[0] = xr.z; t[1] = xr.z;  a = __builtin_elementwise_fma(wiv[2], t, a); \
        t[0] = xr.w; t[1] = xr.w;  a = __builtin_elementwise_fma(wiv[3], t, a); \
        v2f dotv; dotv[0] = c00 + c01; dotv[1] = c10 + c11;                    \
        v2f s2 = a + dotv;                                                     \
        float s0f = xor16_sum(s2[0]);                                          \
        float s1f = xor16_sum(s2[1]);                                          \
        float sv = c ? s1f : s0f;                                              \
        float ev = __builtin_amdgcn_exp2f(sv);                                 \
        float rc = __builtin_amdgcn_rcpf(ev + 1.0f);                           \
        *hw = (_Float16)fmaf(-2.0f, rc, 1.0f);                                 \
    }

#define CHUNK(PBASE)                                                           \
    {                                                                          \
        _Pragma("unroll")                                                      \
        for (int st = 0; st < CH; ++st) STEP(PBASE, st)                        \
    }

    // prologue: 2 chunks in flight
    ISSUE(ldstA, 0)
    ISSUE(ldstB, 1)

    for (int ci = 0; ci < NCH - 2; ci += 2) {
        asm volatile("s_waitcnt vmcnt(1)" ::: "memory");   // chunk ci (A) landed
        CHUNK(rdA)
        ISSUE(ldstA, ci + 2)                                // A free; refill
        asm volatile("s_waitcnt vmcnt(1)" ::: "memory");   // chunk ci+1 (B) landed
        CHUNK(rdB)
        ISSUE(ldstB, ci + 3)                                // B free; refill
    }
    // tail: chunks NCH-2 (A), NCH-1 (B); outstanding = {A, B}
    asm volatile("s_waitcnt vmcnt(1)" ::: "memory");
    CHUNK(rdA)
    asm volatile("s_waitcnt vmcnt(0)" ::: "memory");
    CHUNK(rdB)

#undef CHUNK
#undef STEP
#undef ISSUE

    // ---- epilogue: y = h_T @ W_out^T + b_out ----
    __syncthreads();
    if (tid < ROWS_PER_BLOCK * ODIM) {   // 64 threads
        const int rr = tid >> 3;
        const int o  = tid & 7;
        float acc = b_out[o];
#pragma unroll
        for (int j = 0; j < HDIM; ++j)
            acc = fmaf((float)hsh[rr][j], W_out[o * HDIM + j], acc);
        out[((long long)blockIdx.x * ROWS_PER_BLOCK + rr) * ODIM + o] = acc;
    }
}

extern "C" void kernel_launch(void* const* d_in, const int* in_sizes, int n_in,
                              void* d_out, int out_size, void* d_ws, size_t ws_size,
                              hipStream_t stream) {
    const float* x     = (const float*)d_in[0];
    const float* W_ih  = (const float*)d_in[1];
    const float* W_hh  = (const float*)d_in[2];
    const float* b_ih  = (const float*)d_in[3];
    const float* b_hh  = (const float*)d_in[4];
    const float* W_out = (const float*)d_in[5];
    const float* b_out = (const float*)d_in[6];

    const int B = in_sizes[0] / (T_STEPS * FDIM);   // 4096
    const int grid = B / ROWS_PER_BLOCK;            // 512 blocks = 2/CU

    rnn_scan_kernel<<<grid, 256, 0, stream>>>(
        x, W_ih, W_hh, b_ih, b_hh, W_out, b_out, (float*)d_out);
}